// Round 1
// 831.280 us; speedup vs baseline: 1.0565x; 1.0565x over previous
//
#include <hip/hip_runtime.h>
#include <math.h>

#define B 256
#define N 1000
#define D 256
#define H 8
#define DH 32
#define NEG (-1000000000.0f)

__device__ __forceinline__ float waveReduceMax(float v) {
#pragma unroll
    for (int off = 32; off >= 1; off >>= 1) v = fmaxf(v, __shfl_xor(v, off, 64));
    return v;
}
__device__ __forceinline__ float waveReduceSum(float v) {
#pragma unroll
    for (int off = 32; off >= 1; off >>= 1) v += __shfl_xor(v, off, 64);
    return v;
}

// ---------------------------------------------------------------------------
// K0: mask fix — mask[:,0] |= !any(mask).  One block per batch.
// ---------------------------------------------------------------------------
__global__ __launch_bounds__(256) void k_mask(
    const int* __restrict__ feas, int* __restrict__ mask_ws)
{
    __shared__ int sRed[4];
    const int b = blockIdx.x;
    const int tid = threadIdx.x;
    int vals[4];
    int orloc = 0;
#pragma unroll
    for (int k = 0; k < 4; ++k) {
        int n = tid + k * 256;
        int v = (n < N) ? feas[b * N + n] : 0;
        vals[k] = v;
        orloc |= v;
    }
#pragma unroll
    for (int off = 32; off >= 1; off >>= 1) orloc |= __shfl_xor(orloc, off, 64);
    if ((tid & 63) == 0) sRed[tid >> 6] = orloc;
    __syncthreads();
    const int anyf = sRed[0] | sRed[1] | sRed[2] | sRed[3];
#pragma unroll
    for (int k = 0; k < 4; ++k) {
        int n = tid + k * 256;
        if (n < N) {
            int m = vals[k];
            if (n == 0 && !anyf) m = 1;
            mask_ws[b * N + n] = m;
        }
    }
}

// ---------------------------------------------------------------------------
// K1: step_context GEMV.  grid 512 = (b, col-half).  thread j -> one output col.
// 4 accumulators to break the serial FMA chain and keep >4 loads in flight.
// ---------------------------------------------------------------------------
__global__ __launch_bounds__(256) void k_ctx(
    const float* __restrict__ ne, const float* __restrict__ gc,
    const float* __restrict__ cap, const float* __restrict__ dem,
    const float* __restrict__ rem, const float* __restrict__ Wctx,
    const int* __restrict__ head,
    float* __restrict__ q1_ws, float* __restrict__ q2_ws)
{
    __shared__ float xs[515];
    const int tid = threadIdx.x;
    const int b = blockIdx.x >> 1;
    const int half = blockIdx.x & 1;
    const int hd = head[b];
    for (int i = tid; i < 515; i += 256) {
        float v;
        if (i < 256)       v = ne[(size_t)(b * N + hd) * D + i];
        else if (i < 512)  v = gc[b * D + (i - 256)];
        else if (i == 512) v = cap[b];
        else if (i == 513) v = dem[b];
        else               v = rem[b];
        xs[i] = v;
    }
    __syncthreads();
    const float* __restrict__ wcol = Wctx + half * 256 + tid;
    float a0 = 0.f, a1 = 0.f, a2 = 0.f, a3 = 0.f;
    int i = 0;
#pragma unroll 2
    for (; i + 4 <= 515; i += 4) {
        a0 = fmaf(xs[i + 0], wcol[(i + 0) * 512], a0);
        a1 = fmaf(xs[i + 1], wcol[(i + 1) * 512], a1);
        a2 = fmaf(xs[i + 2], wcol[(i + 2) * 512], a2);
        a3 = fmaf(xs[i + 3], wcol[(i + 3) * 512], a3);
    }
    for (; i < 515; ++i) a0 = fmaf(xs[i], wcol[i * 512], a0);
    float a = (a0 + a1) + (a2 + a3);
    (half ? q2_ws : q1_ws)[b * D + tid] = a;
}

// ---------------------------------------------------------------------------
// K2: dual-query masked attention per (b,h).
// Streaming passes unrolled 4x in the row dim: each thread keeps 4 float4
// loads in flight (128 rows / block-iteration).  Mask applied in the softmax
// pass (coalesced global read); q loaded per-wave directly (no LDS, no
// leading barrier, K loads issue at block start).
// ---------------------------------------------------------------------------
__global__ __launch_bounds__(256) void k_attn(
    const float* __restrict__ gk, const float* __restrict__ gv,
    const float* __restrict__ q1_ws, const float* __restrict__ q2_ws,
    const int* __restrict__ mask_ws,
    float* __restrict__ out1_ws, float* __restrict__ out2_ws)
{
    __shared__ float s1[N];
    __shared__ float s2[N];
    __shared__ float redA[4], redB[4];
    __shared__ __align__(16) float part1[4][DH];
    __shared__ __align__(16) float part2[4][DH];

    const int tid = threadIdx.x;
    const int b = blockIdx.x >> 3;
    const int h = blockIdx.x & 7;
    const int wid = tid >> 6;
    const int lane = tid & 63;
    const int nsub = lane >> 3;   // 0..7
    const int d4 = lane & 7;      // 0..7

    const float4 q1v = ((const float4*)(q1_ws + (size_t)b * D + h * DH))[d4];
    const float4 q2v = ((const float4*)(q2_ws + (size_t)b * D + h * DH))[d4];
    const float scale = 0.17677669529663687f; // 1/sqrt(32)
    const float4* __restrict__ kb = (const float4*)(gk + (size_t)(b * H + h) * N * DH);
    const int rbase = wid * 32 + nsub;        // wave covers rbase + {0,8,16,24}

    // ---- phase 1: scores, 128 rows per iteration, 4 loads in flight ----
#pragma unroll 2
    for (int base = 0; base < 896; base += 128) {
        float4 kv[4];
#pragma unroll
        for (int k = 0; k < 4; ++k) kv[k] = kb[(base + rbase + k * 8) * 8 + d4];
#pragma unroll
        for (int k = 0; k < 4; ++k) {
            float d1 = kv[k].x * q1v.x + kv[k].y * q1v.y + kv[k].z * q1v.z + kv[k].w * q1v.w;
            float d2 = kv[k].x * q2v.x + kv[k].y * q2v.y + kv[k].z * q2v.z + kv[k].w * q2v.w;
            d1 += __shfl_xor(d1, 1, 64); d1 += __shfl_xor(d1, 2, 64); d1 += __shfl_xor(d1, 4, 64);
            d2 += __shfl_xor(d2, 1, 64); d2 += __shfl_xor(d2, 2, 64); d2 += __shfl_xor(d2, 4, 64);
            if (d4 == 0) {
                int r = base + rbase + k * 8;
                s1[r] = d1 * scale;
                s2[r] = d2 * scale;
            }
        }
    }
    {   // tail: rows 896..999
        float4 kv[4];
        int rr[4];
#pragma unroll
        for (int k = 0; k < 4; ++k) {
            rr[k] = 896 + rbase + k * 8;
            kv[k] = (rr[k] < N) ? kb[rr[k] * 8 + d4] : make_float4(0.f, 0.f, 0.f, 0.f);
        }
#pragma unroll
        for (int k = 0; k < 4; ++k) {
            float d1 = kv[k].x * q1v.x + kv[k].y * q1v.y + kv[k].z * q1v.z + kv[k].w * q1v.w;
            float d2 = kv[k].x * q2v.x + kv[k].y * q2v.y + kv[k].z * q2v.z + kv[k].w * q2v.w;
            d1 += __shfl_xor(d1, 1, 64); d1 += __shfl_xor(d1, 2, 64); d1 += __shfl_xor(d1, 4, 64);
            d2 += __shfl_xor(d2, 1, 64); d2 += __shfl_xor(d2, 2, 64); d2 += __shfl_xor(d2, 4, 64);
            if (d4 == 0 && rr[k] < N) {
                s1[rr[k]] = d1 * scale;
                s2[rr[k]] = d2 * scale;
            }
        }
    }
    __syncthreads();

    // ---- phase 2: masked softmax (mask read coalesced from global/L2) ----
    float m1 = -INFINITY, m2 = -INFINITY;
    float v1[4], v2[4];
#pragma unroll
    for (int k = 0; k < 4; ++k) {
        int n = tid + k * 256;
        if (n < N) {
            int mm = mask_ws[b * N + n];
            v1[k] = mm ? s1[n] : NEG;
            v2[k] = mm ? s2[n] : NEG;
            m1 = fmaxf(m1, v1[k]);
            m2 = fmaxf(m2, v2[k]);
        } else { v1[k] = NEG; v2[k] = NEG; }
    }
    m1 = waveReduceMax(m1);
    m2 = waveReduceMax(m2);
    if ((tid & 63) == 0) { redA[wid] = m1; redB[wid] = m2; }
    __syncthreads();
    m1 = fmaxf(fmaxf(redA[0], redA[1]), fmaxf(redA[2], redA[3]));
    m2 = fmaxf(fmaxf(redB[0], redB[1]), fmaxf(redB[2], redB[3]));
    __syncthreads();

    float sum1 = 0.f, sum2 = 0.f;
#pragma unroll
    for (int k = 0; k < 4; ++k) {
        int n = tid + k * 256;
        if (n < N) {
            float e1 = __expf(v1[k] - m1);
            float e2 = __expf(v2[k] - m2);
            s1[n] = e1; s2[n] = e2;
            sum1 += e1; sum2 += e2;
        }
    }
    sum1 = waveReduceSum(sum1);
    sum2 = waveReduceSum(sum2);
    if ((tid & 63) == 0) { redA[wid] = sum1; redB[wid] = sum2; }
    __syncthreads();
    sum1 = redA[0] + redA[1] + redA[2] + redA[3];
    sum2 = redB[0] + redB[1] + redB[2] + redB[3];

    // ---- phase 3: attn @ V, 128 rows per iteration, 4 loads in flight ----
    const float4* __restrict__ vb = (const float4*)(gv + (size_t)(b * H + h) * N * DH);
    float4 a1 = {0.f, 0.f, 0.f, 0.f}, a2 = {0.f, 0.f, 0.f, 0.f};
#pragma unroll 2
    for (int base = 0; base < 896; base += 128) {
        float4 vv[4];
#pragma unroll
        for (int k = 0; k < 4; ++k) vv[k] = vb[(base + rbase + k * 8) * 8 + d4];
#pragma unroll
        for (int k = 0; k < 4; ++k) {
            int r = base + rbase + k * 8;
            float p1 = s1[r], p2 = s2[r];
            a1.x = fmaf(p1, vv[k].x, a1.x); a1.y = fmaf(p1, vv[k].y, a1.y);
            a1.z = fmaf(p1, vv[k].z, a1.z); a1.w = fmaf(p1, vv[k].w, a1.w);
            a2.x = fmaf(p2, vv[k].x, a2.x); a2.y = fmaf(p2, vv[k].y, a2.y);
            a2.z = fmaf(p2, vv[k].z, a2.z); a2.w = fmaf(p2, vv[k].w, a2.w);
        }
    }
    {   // tail: rows 896..999
        float4 vv[4];
        int rr[4];
#pragma unroll
        for (int k = 0; k < 4; ++k) {
            rr[k] = 896 + rbase + k * 8;
            vv[k] = (rr[k] < N) ? vb[rr[k] * 8 + d4] : make_float4(0.f, 0.f, 0.f, 0.f);
        }
#pragma unroll
        for (int k = 0; k < 4; ++k) {
            float p1 = (rr[k] < N) ? s1[rr[k]] : 0.f;
            float p2 = (rr[k] < N) ? s2[rr[k]] : 0.f;
            a1.x = fmaf(p1, vv[k].x, a1.x); a1.y = fmaf(p1, vv[k].y, a1.y);
            a1.z = fmaf(p1, vv[k].z, a1.z); a1.w = fmaf(p1, vv[k].w, a1.w);
            a2.x = fmaf(p2, vv[k].x, a2.x); a2.y = fmaf(p2, vv[k].y, a2.y);
            a2.z = fmaf(p2, vv[k].z, a2.z); a2.w = fmaf(p2, vv[k].w, a2.w);
        }
    }
    // reduce across the 8 nsub groups (lanes sharing d4)
#pragma unroll
    for (int off = 8; off <= 32; off <<= 1) {
        a1.x += __shfl_xor(a1.x, off, 64); a1.y += __shfl_xor(a1.y, off, 64);
        a1.z += __shfl_xor(a1.z, off, 64); a1.w += __shfl_xor(a1.w, off, 64);
        a2.x += __shfl_xor(a2.x, off, 64); a2.y += __shfl_xor(a2.y, off, 64);
        a2.z += __shfl_xor(a2.z, off, 64); a2.w += __shfl_xor(a2.w, off, 64);
    }
    if (lane < 8) {
        ((float4*)part1[wid])[d4] = a1;
        ((float4*)part2[wid])[d4] = a2;
    }
    __syncthreads();

    if (tid < 64) {
        int set = tid >> 5, d = tid & 31;
        float tot = set ? (part2[0][d] + part2[1][d] + part2[2][d] + part2[3][d])
                        : (part1[0][d] + part1[1][d] + part1[2][d] + part1[3][d]);
        float rs = 1.f / (set ? sum2 : sum1);
        (set ? out2_ws : out1_ws)[b * D + h * DH + d] = tot * rs;
    }
}

// ---------------------------------------------------------------------------
// K3: glimpse = out1 @ W_out ; head_encoding = out2 @ W_sa
// ---------------------------------------------------------------------------
__global__ __launch_bounds__(256) void k_proj(
    const float* __restrict__ out1_ws, const float* __restrict__ out2_ws,
    const float* __restrict__ Wout, const float* __restrict__ Wsa,
    float* __restrict__ glimpse_ws, float* __restrict__ head_enc)
{
    __shared__ float x[D];
    const int tid = threadIdx.x;
    const int b = blockIdx.x >> 1;
    const int which = blockIdx.x & 1;
    const float* __restrict__ src = which ? out2_ws : out1_ws;
    x[tid] = src[b * D + tid];
    __syncthreads();
    const float* __restrict__ W = which ? Wsa : Wout;
    float a = 0.f;
#pragma unroll 8
    for (int i = 0; i < D; ++i) a = fmaf(x[i], W[i * D + tid], a);
    (which ? head_enc : glimpse_ws)[b * D + tid] = a;
}

// ---------------------------------------------------------------------------
// K4: logits GEMV, wave-per-row, unrolled x4 (4 loads in flight per thread).
// grid B*4 blocks (250 rows each), 256 threads (4 waves)
// ---------------------------------------------------------------------------
__global__ __launch_bounds__(256) void k_logits(
    const float* __restrict__ lk, const float* __restrict__ glimpse_ws,
    const int* __restrict__ mask_ws, float* __restrict__ logits_ws)
{
    __shared__ __align__(16) float gsh[D];
    const int tid = threadIdx.x;
    const int b = blockIdx.x >> 2;
    const int chunk = blockIdx.x & 3;
    gsh[tid] = glimpse_ws[b * D + tid];
    __syncthreads();

    const int lane = tid & 63, wid = tid >> 6;
    const float4 gv = ((const float4*)gsh)[lane];
    const int n0 = chunk * 250;
    const int nend = n0 + 250;
    for (int n = n0 + wid * 4; n < nend; n += 16) {
        float4 kr[4];
#pragma unroll
        for (int j = 0; j < 4; ++j) {
            int nn = n + j;
            kr[j] = (nn < nend) ? ((const float4*)(lk + (size_t)(b * N + nn) * D))[lane]
                                : make_float4(0.f, 0.f, 0.f, 0.f);
        }
        float p[4];
#pragma unroll
        for (int j = 0; j < 4; ++j)
            p[j] = kr[j].x * gv.x + kr[j].y * gv.y + kr[j].z * gv.z + kr[j].w * gv.w;
#pragma unroll
        for (int off = 32; off >= 1; off >>= 1) {
#pragma unroll
            for (int j = 0; j < 4; ++j) p[j] += __shfl_xor(p[j], off, 64);
        }
        if (lane == 0) {
#pragma unroll
            for (int j = 0; j < 4; ++j) {
                int nn = n + j;
                if (nn < nend) {
                    float l = 10.0f * tanhf(p[j] * 0.0625f);
                    logits_ws[b * N + nn] = mask_ws[b * N + nn] ? l : NEG;
                }
            }
        }
    }
}

// ---------------------------------------------------------------------------
// K5: log_softmax over each row of logits.  grid B blocks.
// ---------------------------------------------------------------------------
__global__ __launch_bounds__(256) void k_logsoftmax(
    const float* __restrict__ logits_ws, float* __restrict__ logp)
{
    __shared__ float red[4];
    const int tid = threadIdx.x;
    const int b = blockIdx.x;
    float v[4];
    float m = -INFINITY;
#pragma unroll
    for (int k = 0; k < 4; ++k) {
        int n = tid + k * 256;
        v[k] = (n < N) ? logits_ws[b * N + n] : -INFINITY;
        m = fmaxf(m, v[k]);
    }
    m = waveReduceMax(m);
    if ((tid & 63) == 0) red[tid >> 6] = m;
    __syncthreads();
    m = fmaxf(fmaxf(red[0], red[1]), fmaxf(red[2], red[3]));
    __syncthreads();
    float s = 0.f;
#pragma unroll
    for (int k = 0; k < 4; ++k) {
        int n = tid + k * 256;
        if (n < N) s += __expf(v[k] - m);
    }
    s = waveReduceSum(s);
    if ((tid & 63) == 0) red[tid >> 6] = s;
    __syncthreads();
    s = red[0] + red[1] + red[2] + red[3];
    const float lse = m + logf(s);
#pragma unroll
    for (int k = 0; k < 4; ++k) {
        int n = tid + k * 256;
        if (n < N) logp[b * N + n] = v[k] - lse;
    }
}

extern "C" void kernel_launch(void* const* d_in, const int* in_sizes, int n_in,
                              void* d_out, int out_size, void* d_ws, size_t ws_size,
                              hipStream_t stream) {
    const float* ne   = (const float*)d_in[0];
    const float* gc   = (const float*)d_in[1];
    const float* gk   = (const float*)d_in[2];
    const float* gvv  = (const float*)d_in[3];
    const float* lk   = (const float*)d_in[4];
    const float* cap  = (const float*)d_in[5];
    const float* dem  = (const float*)d_in[6];
    const float* rem  = (const float*)d_in[7];
    const float* Wctx = (const float*)d_in[8];
    const float* Wout = (const float*)d_in[9];
    const float* Wsa  = (const float*)d_in[10];
    const int*   head = (const int*)d_in[11];
    const int*   feas = (const int*)d_in[12];
    float* out = (float*)d_out;

    float* ws        = (float*)d_ws;
    float* q1_ws     = ws;                        // B*D
    float* q2_ws     = q1_ws + B * D;             // B*D
    int*   mask_ws   = (int*)(q2_ws + B * D);     // B*N ints
    float* out1_ws   = (float*)(mask_ws + B * N); // B*D
    float* out2_ws   = out1_ws + B * D;           // B*D
    float* glimpse_ws= out2_ws + B * D;           // B*D
    float* logits_ws = glimpse_ws + B * D;        // B*N

    hipLaunchKernelGGL(k_mask, dim3(B), dim3(256), 0, stream, feas, mask_ws);
    hipLaunchKernelGGL(k_ctx, dim3(B * 2), dim3(256), 0, stream,
                       ne, gc, cap, dem, rem, Wctx, head, q1_ws, q2_ws);
    hipLaunchKernelGGL(k_attn, dim3(B * H), dim3(256), 0, stream,
                       gk, gvv, q1_ws, q2_ws, mask_ws, out1_ws, out2_ws);
    hipLaunchKernelGGL(k_proj, dim3(B * 2), dim3(256), 0, stream,
                       out1_ws, out2_ws, Wout, Wsa, glimpse_ws, out + B * N);
    hipLaunchKernelGGL(k_logits, dim3(B * 4), dim3(256), 0, stream,
                       lk, glimpse_ws, mask_ws, logits_ws);
    hipLaunchKernelGGL(k_logsoftmax, dim3(B), dim3(256), 0, stream,
                       logits_ws, out);
}

// Round 2
// 815.012 us; speedup vs baseline: 1.0776x; 1.0200x over previous
//
#include <hip/hip_runtime.h>
#include <math.h>

#define B 256
#define N 1000
#define D 256
#define H 8
#define DH 32
#define NEG (-1000000000.0f)

__device__ __forceinline__ float waveReduceMax(float v) {
#pragma unroll
    for (int off = 32; off >= 1; off >>= 1) v = fmaxf(v, __shfl_xor(v, off, 64));
    return v;
}
__device__ __forceinline__ float waveReduceSum(float v) {
#pragma unroll
    for (int off = 32; off >= 1; off >>= 1) v += __shfl_xor(v, off, 64);
    return v;
}

// DPP-based lane-xor adds: VALU pipe, no LDS-pipe traffic.
// quad_perm [1,0,3,2] = 0xB1 (xor1), [2,3,0,1] = 0x4E (xor2).
__device__ __forceinline__ float qxor1_add(float v) {
    int t = __builtin_amdgcn_update_dpp(0, __float_as_int(v), 0xB1, 0xF, 0xF, true);
    return v + __int_as_float(t);
}
__device__ __forceinline__ float qxor2_add(float v) {
    int t = __builtin_amdgcn_update_dpp(0, __float_as_int(v), 0x4E, 0xF, 0xF, true);
    return v + __int_as_float(t);
}
// ds_swizzle BitMode: offset = (xor<<10)|(or<<5)|and ; xor4 within 32-lane group.
__device__ __forceinline__ float sxor4_add(float v) {
    int t = __builtin_amdgcn_ds_swizzle(__float_as_int(v), 0x101F);
    return v + __int_as_float(t);
}
__device__ __forceinline__ float dot4(float4 a, float4 b) {
    return a.x * b.x + a.y * b.y + a.z * b.z + a.w * b.w;
}

// ---------------------------------------------------------------------------
// K0: mask fix — mask[:,0] |= !any(mask).  One block per batch.
// ---------------------------------------------------------------------------
__global__ __launch_bounds__(256) void k_mask(
    const int* __restrict__ feas, int* __restrict__ mask_ws)
{
    __shared__ int sRed[4];
    const int b = blockIdx.x;
    const int tid = threadIdx.x;
    int vals[4];
    int orloc = 0;
#pragma unroll
    for (int k = 0; k < 4; ++k) {
        int n = tid + k * 256;
        int v = (n < N) ? feas[b * N + n] : 0;
        vals[k] = v;
        orloc |= v;
    }
#pragma unroll
    for (int off = 32; off >= 1; off >>= 1) orloc |= __shfl_xor(orloc, off, 64);
    if ((tid & 63) == 0) sRed[tid >> 6] = orloc;
    __syncthreads();
    const int anyf = sRed[0] | sRed[1] | sRed[2] | sRed[3];
#pragma unroll
    for (int k = 0; k < 4; ++k) {
        int n = tid + k * 256;
        if (n < N) {
            int m = vals[k];
            if (n == 0 && !anyf) m = 1;
            mask_ws[b * N + n] = m;
        }
    }
}

// ---------------------------------------------------------------------------
// K1: step_context GEMV.  grid 512 = (b, col-half).  thread j -> one output col.
// ---------------------------------------------------------------------------
__global__ __launch_bounds__(256) void k_ctx(
    const float* __restrict__ ne, const float* __restrict__ gc,
    const float* __restrict__ cap, const float* __restrict__ dem,
    const float* __restrict__ rem, const float* __restrict__ Wctx,
    const int* __restrict__ head,
    float* __restrict__ q1_ws, float* __restrict__ q2_ws)
{
    __shared__ float xs[515];
    const int tid = threadIdx.x;
    const int b = blockIdx.x >> 1;
    const int half = blockIdx.x & 1;
    const int hd = head[b];
    for (int i = tid; i < 515; i += 256) {
        float v;
        if (i < 256)       v = ne[(size_t)(b * N + hd) * D + i];
        else if (i < 512)  v = gc[b * D + (i - 256)];
        else if (i == 512) v = cap[b];
        else if (i == 513) v = dem[b];
        else               v = rem[b];
        xs[i] = v;
    }
    __syncthreads();
    const float* __restrict__ wcol = Wctx + half * 256 + tid;
    float a0 = 0.f, a1 = 0.f, a2 = 0.f, a3 = 0.f;
    int i = 0;
#pragma unroll 2
    for (; i + 4 <= 515; i += 4) {
        a0 = fmaf(xs[i + 0], wcol[(i + 0) * 512], a0);
        a1 = fmaf(xs[i + 1], wcol[(i + 1) * 512], a1);
        a2 = fmaf(xs[i + 2], wcol[(i + 2) * 512], a2);
        a3 = fmaf(xs[i + 3], wcol[(i + 3) * 512], a3);
    }
    for (; i < 515; ++i) a0 = fmaf(xs[i], wcol[i * 512], a0);
    float a = (a0 + a1) + (a2 + a3);
    (half ? q2_ws : q1_ws)[b * D + tid] = a;
}

// ---------------------------------------------------------------------------
// K2: dual-query masked attention per (b,h).
// 8 float4 loads in flight per thread (256 rows / block-iteration).
// Cross-lane dot reduce: 2x DPP quad_perm adds (VALU) + 1 ds_swizzle (xor4)
// per query -> 2 LDS-pipe ops per KB streamed instead of 6.
// ---------------------------------------------------------------------------
__global__ __launch_bounds__(256) void k_attn(
    const float* __restrict__ gk, const float* __restrict__ gv,
    const float* __restrict__ q1_ws, const float* __restrict__ q2_ws,
    const int* __restrict__ mask_ws,
    float* __restrict__ out1_ws, float* __restrict__ out2_ws)
{
    __shared__ float s1[N];
    __shared__ float s2[N];
    __shared__ float redA[4], redB[4];
    __shared__ __align__(16) float part1[4][DH];
    __shared__ __align__(16) float part2[4][DH];

    const int tid = threadIdx.x;
    const int b = blockIdx.x >> 3;
    const int h = blockIdx.x & 7;
    const int wid = tid >> 6;
    const int lane = tid & 63;
    const int nsub = lane >> 3;   // 0..7
    const int d4 = lane & 7;      // 0..7

    const float4 q1v = ((const float4*)(q1_ws + (size_t)b * D + h * DH))[d4];
    const float4 q2v = ((const float4*)(q2_ws + (size_t)b * D + h * DH))[d4];
    const float scale = 0.17677669529663687f; // 1/sqrt(32)
    const float4* __restrict__ kb = (const float4*)(gk + (size_t)(b * H + h) * N * DH);
    const int rb8 = wid * 64 + nsub;   // wave covers rb8 + {0,8,...,56}

    // ---- phase 1: scores, 256 rows / block-iteration, 8 loads in flight ----
#pragma unroll 1
    for (int base = 0; base < 768; base += 256) {
        float4 kv[8];
#pragma unroll
        for (int k = 0; k < 8; ++k) kv[k] = kb[(base + rb8 + k * 8) * 8 + d4];
#pragma unroll
        for (int k = 0; k < 8; ++k) {
            float d1 = dot4(kv[k], q1v);
            float d2 = dot4(kv[k], q2v);
            d1 = qxor1_add(d1); d1 = qxor2_add(d1); d1 = sxor4_add(d1);
            d2 = qxor1_add(d2); d2 = qxor2_add(d2); d2 = sxor4_add(d2);
            if (d4 == 0) {
                int r = base + rb8 + k * 8;
                s1[r] = d1 * scale;
                s2[r] = d2 * scale;
            }
        }
    }
    {   // tail: rows 768..999
        float4 kv[8];
        int rr[8];
#pragma unroll
        for (int k = 0; k < 8; ++k) {
            rr[k] = 768 + rb8 + k * 8;
            kv[k] = (rr[k] < N) ? kb[rr[k] * 8 + d4] : make_float4(0.f, 0.f, 0.f, 0.f);
        }
#pragma unroll
        for (int k = 0; k < 8; ++k) {
            float d1 = dot4(kv[k], q1v);
            float d2 = dot4(kv[k], q2v);
            d1 = qxor1_add(d1); d1 = qxor2_add(d1); d1 = sxor4_add(d1);
            d2 = qxor1_add(d2); d2 = qxor2_add(d2); d2 = sxor4_add(d2);
            if (d4 == 0 && rr[k] < N) {
                s1[rr[k]] = d1 * scale;
                s2[rr[k]] = d2 * scale;
            }
        }
    }
    __syncthreads();

    // ---- phase 2: masked softmax (mask read coalesced from global/L2) ----
    float m1 = -INFINITY, m2 = -INFINITY;
    float v1[4], v2[4];
#pragma unroll
    for (int k = 0; k < 4; ++k) {
        int n = tid + k * 256;
        if (n < N) {
            int mm = mask_ws[b * N + n];
            v1[k] = mm ? s1[n] : NEG;
            v2[k] = mm ? s2[n] : NEG;
            m1 = fmaxf(m1, v1[k]);
            m2 = fmaxf(m2, v2[k]);
        } else { v1[k] = NEG; v2[k] = NEG; }
    }
    m1 = waveReduceMax(m1);
    m2 = waveReduceMax(m2);
    if ((tid & 63) == 0) { redA[wid] = m1; redB[wid] = m2; }
    __syncthreads();
    m1 = fmaxf(fmaxf(redA[0], redA[1]), fmaxf(redA[2], redA[3]));
    m2 = fmaxf(fmaxf(redB[0], redB[1]), fmaxf(redB[2], redB[3]));
    __syncthreads();

    float sum1 = 0.f, sum2 = 0.f;
#pragma unroll
    for (int k = 0; k < 4; ++k) {
        int n = tid + k * 256;
        if (n < N) {
            float e1 = __expf(v1[k] - m1);
            float e2 = __expf(v2[k] - m2);
            s1[n] = e1; s2[n] = e2;
            sum1 += e1; sum2 += e2;
        }
    }
    sum1 = waveReduceSum(sum1);
    sum2 = waveReduceSum(sum2);
    if ((tid & 63) == 0) { redA[wid] = sum1; redB[wid] = sum2; }
    __syncthreads();
    sum1 = redA[0] + redA[1] + redA[2] + redA[3];
    sum2 = redB[0] + redB[1] + redB[2] + redB[3];

    // ---- phase 3: attn @ V, 8 loads in flight ----
    const float4* __restrict__ vb = (const float4*)(gv + (size_t)(b * H + h) * N * DH);
    float4 a1 = {0.f, 0.f, 0.f, 0.f}, a2 = {0.f, 0.f, 0.f, 0.f};
#pragma unroll 1
    for (int base = 0; base < 768; base += 256) {
        float4 vv[8];
#pragma unroll
        for (int k = 0; k < 8; ++k) vv[k] = vb[(base + rb8 + k * 8) * 8 + d4];
#pragma unroll
        for (int k = 0; k < 8; ++k) {
            int r = base + rb8 + k * 8;
            float p1 = s1[r], p2 = s2[r];
            a1.x = fmaf(p1, vv[k].x, a1.x); a1.y = fmaf(p1, vv[k].y, a1.y);
            a1.z = fmaf(p1, vv[k].z, a1.z); a1.w = fmaf(p1, vv[k].w, a1.w);
            a2.x = fmaf(p2, vv[k].x, a2.x); a2.y = fmaf(p2, vv[k].y, a2.y);
            a2.z = fmaf(p2, vv[k].z, a2.z); a2.w = fmaf(p2, vv[k].w, a2.w);
        }
    }
    {   // tail: rows 768..999
        float4 vv[8];
        int rr[8];
#pragma unroll
        for (int k = 0; k < 8; ++k) {
            rr[k] = 768 + rb8 + k * 8;
            vv[k] = (rr[k] < N) ? vb[rr[k] * 8 + d4] : make_float4(0.f, 0.f, 0.f, 0.f);
        }
#pragma unroll
        for (int k = 0; k < 8; ++k) {
            float p1 = (rr[k] < N) ? s1[rr[k]] : 0.f;
            float p2 = (rr[k] < N) ? s2[rr[k]] : 0.f;
            a1.x = fmaf(p1, vv[k].x, a1.x); a1.y = fmaf(p1, vv[k].y, a1.y);
            a1.z = fmaf(p1, vv[k].z, a1.z); a1.w = fmaf(p1, vv[k].w, a1.w);
            a2.x = fmaf(p2, vv[k].x, a2.x); a2.y = fmaf(p2, vv[k].y, a2.y);
            a2.z = fmaf(p2, vv[k].z, a2.z); a2.w = fmaf(p2, vv[k].w, a2.w);
        }
    }
    // reduce across the 8 nsub groups (lanes sharing d4)
#pragma unroll
    for (int off = 8; off <= 32; off <<= 1) {
        a1.x += __shfl_xor(a1.x, off, 64); a1.y += __shfl_xor(a1.y, off, 64);
        a1.z += __shfl_xor(a1.z, off, 64); a1.w += __shfl_xor(a1.w, off, 64);
        a2.x += __shfl_xor(a2.x, off, 64); a2.y += __shfl_xor(a2.y, off, 64);
        a2.z += __shfl_xor(a2.z, off, 64); a2.w += __shfl_xor(a2.w, off, 64);
    }
    if (lane < 8) {
        ((float4*)part1[wid])[d4] = a1;
        ((float4*)part2[wid])[d4] = a2;
    }
    __syncthreads();

    if (tid < 64) {
        int set = tid >> 5, d = tid & 31;
        float tot = set ? (part2[0][d] + part2[1][d] + part2[2][d] + part2[3][d])
                        : (part1[0][d] + part1[1][d] + part1[2][d] + part1[3][d]);
        float rs = 1.f / (set ? sum2 : sum1);
        (set ? out2_ws : out1_ws)[b * D + h * DH + d] = tot * rs;
    }
}

// ---------------------------------------------------------------------------
// K3: glimpse = out1 @ W_out ; head_encoding = out2 @ W_sa
// ---------------------------------------------------------------------------
__global__ __launch_bounds__(256) void k_proj(
    const float* __restrict__ out1_ws, const float* __restrict__ out2_ws,
    const float* __restrict__ Wout, const float* __restrict__ Wsa,
    float* __restrict__ glimpse_ws, float* __restrict__ head_enc)
{
    __shared__ float x[D];
    const int tid = threadIdx.x;
    const int b = blockIdx.x >> 1;
    const int which = blockIdx.x & 1;
    const float* __restrict__ src = which ? out2_ws : out1_ws;
    x[tid] = src[b * D + tid];
    __syncthreads();
    const float* __restrict__ W = which ? Wsa : Wout;
    float a = 0.f;
#pragma unroll 8
    for (int i = 0; i < D; ++i) a = fmaf(x[i], W[i * D + tid], a);
    (which ? head_enc : glimpse_ws)[b * D + tid] = a;
}

// ---------------------------------------------------------------------------
// K4: logits GEMV.  8-lane group owns a full row (1KB) across 8 column
// chunks; glimpse chunks preloaded to registers.  Per 8KB: 8 loads in
// flight + 32 FMA + 2 DPP + 1 swizzle.  grid B*4, 256 threads.
// ---------------------------------------------------------------------------
__global__ __launch_bounds__(256) void k_logits(
    const float* __restrict__ lk, const float* __restrict__ glimpse_ws,
    const int* __restrict__ mask_ws, float* __restrict__ logits_ws)
{
    __shared__ __align__(16) float gsh[D];
    const int tid = threadIdx.x;
    const int b = blockIdx.x >> 2;
    const int chunk = blockIdx.x & 3;
    gsh[tid] = glimpse_ws[b * D + tid];
    __syncthreads();

    const int lane = tid & 63, wid = tid >> 6;
    const int rs = lane >> 3;   // row within wave's 8-row group
    const int c  = lane & 7;    // column-chunk id
    float4 g[8];
#pragma unroll
    for (int j = 0; j < 8; ++j) g[j] = ((const float4*)gsh)[c + 8 * j];

    const int n0 = chunk * 250;
    const int nend = n0 + 250;
    const float4* __restrict__ lkb = (const float4*)(lk + (size_t)b * N * D);

#pragma unroll 1
    for (int it = 0; it < 8; ++it) {
        const int r = n0 + it * 32 + wid * 8 + rs;
        const bool ok = (r < nend);
        float4 kv[8];
#pragma unroll
        for (int j = 0; j < 8; ++j)
            kv[j] = ok ? lkb[(size_t)r * 64 + c + 8 * j]
                       : make_float4(0.f, 0.f, 0.f, 0.f);
        float p = 0.f;
#pragma unroll
        for (int j = 0; j < 8; ++j) p += dot4(kv[j], g[j]);
        p = qxor1_add(p); p = qxor2_add(p); p = sxor4_add(p);
        if (c == 0 && ok) {
            float l = 10.0f * tanhf(p * 0.0625f);
            logits_ws[b * N + r] = mask_ws[b * N + r] ? l : NEG;
        }
    }
}

// ---------------------------------------------------------------------------
// K5: log_softmax over each row of logits.  grid B blocks.
// ---------------------------------------------------------------------------
__global__ __launch_bounds__(256) void k_logsoftmax(
    const float* __restrict__ logits_ws, float* __restrict__ logp)
{
    __shared__ float red[4];
    const int tid = threadIdx.x;
    const int b = blockIdx.x;
    float v[4];
    float m = -INFINITY;
#pragma unroll
    for (int k = 0; k < 4; ++k) {
        int n = tid + k * 256;
        v[k] = (n < N) ? logits_ws[b * N + n] : -INFINITY;
        m = fmaxf(m, v[k]);
    }
    m = waveReduceMax(m);
    if ((tid & 63) == 0) red[tid >> 6] = m;
    __syncthreads();
    m = fmaxf(fmaxf(red[0], red[1]), fmaxf(red[2], red[3]));
    __syncthreads();
    float s = 0.f;
#pragma unroll
    for (int k = 0; k < 4; ++k) {
        int n = tid + k * 256;
        if (n < N) s += __expf(v[k] - m);
    }
    s = waveReduceSum(s);
    if ((tid & 63) == 0) red[tid >> 6] = s;
    __syncthreads();
    s = red[0] + red[1] + red[2] + red[3];
    const float lse = m + logf(s);
#pragma unroll
    for (int k = 0; k < 4; ++k) {
        int n = tid + k * 256;
        if (n < N) logp[b * N + n] = v[k] - lse;
    }
}

extern "C" void kernel_launch(void* const* d_in, const int* in_sizes, int n_in,
                              void* d_out, int out_size, void* d_ws, size_t ws_size,
                              hipStream_t stream) {
    const float* ne   = (const float*)d_in[0];
    const float* gc   = (const float*)d_in[1];
    const float* gk   = (const float*)d_in[2];
    const float* gvv  = (const float*)d_in[3];
    const float* lk   = (const float*)d_in[4];
    const float* cap  = (const float*)d_in[5];
    const float* dem  = (const float*)d_in[6];
    const float* rem  = (const float*)d_in[7];
    const float* Wctx = (const float*)d_in[8];
    const float* Wout = (const float*)d_in[9];
    const float* Wsa  = (const float*)d_in[10];
    const int*   head = (const int*)d_in[11];
    const int*   feas = (const int*)d_in[12];
    float* out = (float*)d_out;

    float* ws        = (float*)d_ws;
    float* q1_ws     = ws;                        // B*D
    float* q2_ws     = q1_ws + B * D;             // B*D
    int*   mask_ws   = (int*)(q2_ws + B * D);     // B*N ints
    float* out1_ws   = (float*)(mask_ws + B * N); // B*D
    float* out2_ws   = out1_ws + B * D;           // B*D
    float* glimpse_ws= out2_ws + B * D;           // B*D
    float* logits_ws = glimpse_ws + B * D;        // B*N

    hipLaunchKernelGGL(k_mask, dim3(B), dim3(256), 0, stream, feas, mask_ws);
    hipLaunchKernelGGL(k_ctx, dim3(B * 2), dim3(256), 0, stream,
                       ne, gc, cap, dem, rem, Wctx, head, q1_ws, q2_ws);
    hipLaunchKernelGGL(k_attn, dim3(B * H), dim3(256), 0, stream,
                       gk, gvv, q1_ws, q2_ws, mask_ws, out1_ws, out2_ws);
    hipLaunchKernelGGL(k_proj, dim3(B * 2), dim3(256), 0, stream,
                       out1_ws, out2_ws, Wout, Wsa, glimpse_ws, out + B * N);
    hipLaunchKernelGGL(k_logits, dim3(B * 4), dim3(256), 0, stream,
                       lk, glimpse_ws, mask_ws, logits_ws);
    hipLaunchKernelGGL(k_logsoftmax, dim3(B), dim3(256), 0, stream,
                       logits_ws, out);
}

// Round 3
// 791.454 us; speedup vs baseline: 1.1097x; 1.0298x over previous
//
#include <hip/hip_runtime.h>
#include <math.h>

#define B 256
#define N 1000
#define D 256
#define H 8
#define DH 32
#define NEG (-1000000000.0f)

__device__ __forceinline__ float waveReduceMax(float v) {
#pragma unroll
    for (int off = 32; off >= 1; off >>= 1) v = fmaxf(v, __shfl_xor(v, off, 64));
    return v;
}
__device__ __forceinline__ float waveReduceSum(float v) {
#pragma unroll
    for (int off = 32; off >= 1; off >>= 1) v += __shfl_xor(v, off, 64);
    return v;
}
// DPP quad_perm adds (VALU pipe): xor1 = [1,0,3,2] = 0xB1, xor2 = [2,3,0,1] = 0x4E.
__device__ __forceinline__ float qxor1_add(float v) {
    int t = __builtin_amdgcn_update_dpp(0, __float_as_int(v), 0xB1, 0xF, 0xF, true);
    return v + __int_as_float(t);
}
__device__ __forceinline__ float qxor2_add(float v) {
    int t = __builtin_amdgcn_update_dpp(0, __float_as_int(v), 0x4E, 0xF, 0xF, true);
    return v + __int_as_float(t);
}
// ds_swizzle BitMode xor4: offset = (4<<10)|0x1F
__device__ __forceinline__ float sxor4_add(float v) {
    int t = __builtin_amdgcn_ds_swizzle(__float_as_int(v), 0x101F);
    return v + __int_as_float(t);
}
__device__ __forceinline__ float dot4(float4 a, float4 b) {
    return a.x * b.x + a.y * b.y + a.z * b.z + a.w * b.w;
}

// ---------------------------------------------------------------------------
// K1: step_context GEMV.  grid 512 = (b, col-half).  thread j -> one output col.
// ---------------------------------------------------------------------------
__global__ __launch_bounds__(256) void k_ctx(
    const float* __restrict__ ne, const float* __restrict__ gc,
    const float* __restrict__ cap, const float* __restrict__ dem,
    const float* __restrict__ rem, const float* __restrict__ Wctx,
    const int* __restrict__ head,
    float* __restrict__ q1_ws, float* __restrict__ q2_ws)
{
    __shared__ float xs[515];
    const int tid = threadIdx.x;
    const int b = blockIdx.x >> 1;
    const int half = blockIdx.x & 1;
    const int hd = head[b];
    for (int i = tid; i < 515; i += 256) {
        float v;
        if (i < 256)       v = ne[(size_t)(b * N + hd) * D + i];
        else if (i < 512)  v = gc[b * D + (i - 256)];
        else if (i == 512) v = cap[b];
        else if (i == 513) v = dem[b];
        else               v = rem[b];
        xs[i] = v;
    }
    __syncthreads();
    const float* __restrict__ wcol = Wctx + half * 256 + tid;
    float a0 = 0.f, a1 = 0.f, a2 = 0.f, a3 = 0.f;
    int i = 0;
#pragma unroll 2
    for (; i + 4 <= 515; i += 4) {
        a0 = fmaf(xs[i + 0], wcol[(i + 0) * 512], a0);
        a1 = fmaf(xs[i + 1], wcol[(i + 1) * 512], a1);
        a2 = fmaf(xs[i + 2], wcol[(i + 2) * 512], a2);
        a3 = fmaf(xs[i + 3], wcol[(i + 3) * 512], a3);
    }
    for (; i < 515; ++i) a0 = fmaf(xs[i], wcol[i * 512], a0);
    float a = (a0 + a1) + (a2 + a3);
    (half ? q2_ws : q1_ws)[b * D + tid] = a;
}

// ---------------------------------------------------------------------------
// MEGA: one block per batch element.  1024 threads = 16 waves.
//   P0 mask+q load | P1 scores (2 waves/head) | P2 per-wave softmax
//   P3 PV + combine | P4 dual projection | P5 logits stream | P6 log_softmax
// All intermediates live in LDS (~82 KB); only K/V/lk streams touch HBM.
// ---------------------------------------------------------------------------
__global__ __launch_bounds__(1024) void k_mega(
    const float* __restrict__ gk, const float* __restrict__ gv,
    const float* __restrict__ lk,
    const float* __restrict__ q1_ws, const float* __restrict__ q2_ws,
    const float* __restrict__ Wout, const float* __restrict__ Wsa,
    const int* __restrict__ feas,
    float* __restrict__ logp, float* __restrict__ henc_out)
{
    __shared__ float s1[H][N];                      // 32000 B
    __shared__ float s2[H][N];                      // 32000 B
    __shared__ int   smask[N];                      // 4000 B
    __shared__ __align__(16) float q1s[D];          // 1 KB
    __shared__ __align__(16) float q2s[D];          // 1 KB
    __shared__ int   redOi[16];
    __shared__ float redSum[H][2];
    __shared__ __align__(16) float part1[H][2][DH]; // 2 KB
    __shared__ __align__(16) float part2[H][2][DH]; // 2 KB
    __shared__ float out1s[D], out2s[D];            // 2 KB
    __shared__ float gpart[2][D], hpart[2][D];      // 4 KB
    __shared__ __align__(16) float glimpse_s[D];    // 1 KB
    __shared__ float logits_s[N];                   // 4 KB
    __shared__ float redM[16], redS[16];

    const int tid  = threadIdx.x;
    const int b    = blockIdx.x;
    const int wid  = tid >> 6;
    const int lane = tid & 63;

    // ---- P0: mask fix + q staging ----
    int mv = (tid < N) ? feas[b * N + tid] : 0;
    int orloc = mv;
#pragma unroll
    for (int off = 32; off >= 1; off >>= 1) orloc |= __shfl_xor(orloc, off, 64);
    if (lane == 0) redOi[wid] = orloc;
    if (tid < 512) {
        float qv = (tid < 256 ? q1_ws : q2_ws)[b * D + (tid & 255)];
        (tid < 256 ? q1s : q2s)[tid & 255] = qv;
    }
    __syncthreads();
    if (tid < N) {
        int anyf = 0;
#pragma unroll
        for (int i = 0; i < 16; ++i) anyf |= redOi[i];
        smask[tid] = (tid == 0 && !anyf) ? 1 : mv;
    }
    __syncthreads();

    // ---- P1: scores.  wave w -> head w>>1, half w&1.  8 loads in flight. ----
    const int h    = wid >> 1;
    const int half = wid & 1;
    const int nsub = lane >> 3;   // 0..7
    const int d4   = lane & 7;    // 0..7
    const int r0   = half * 8 + nsub;   // 0..15; +16k tiles 128 rows per it
    const float4 q1v = ((const float4*)(q1s + h * DH))[d4];
    const float4 q2v = ((const float4*)(q2s + h * DH))[d4];
    const float scale = 0.17677669529663687f; // 1/sqrt(32)
    const float4* __restrict__ kb = (const float4*)(gk + (size_t)(b * H + h) * N * DH);

#pragma unroll 1
    for (int it = 0; it < 7; ++it) {
        const int rbase = it * 128 + r0;
        float4 kv[8];
#pragma unroll
        for (int k = 0; k < 8; ++k) kv[k] = kb[(rbase + 16 * k) * 8 + d4];
#pragma unroll
        for (int k = 0; k < 8; ++k) {
            float d1 = dot4(kv[k], q1v);
            float d2 = dot4(kv[k], q2v);
            d1 = qxor1_add(d1); d1 = qxor2_add(d1); d1 = sxor4_add(d1);
            d2 = qxor1_add(d2); d2 = qxor2_add(d2); d2 = sxor4_add(d2);
            if (d4 == 0) {
                int r = rbase + 16 * k;
                int m = smask[r];
                s1[h][r] = m ? d1 * scale : NEG;
                s2[h][r] = m ? d2 * scale : NEG;
            }
        }
    }
    {   // tail rows 896..999
        float4 kv[8]; int rr[8];
#pragma unroll
        for (int k = 0; k < 8; ++k) {
            rr[k] = 896 + r0 + 16 * k;
            kv[k] = (rr[k] < N) ? kb[rr[k] * 8 + d4] : make_float4(0.f, 0.f, 0.f, 0.f);
        }
#pragma unroll
        for (int k = 0; k < 8; ++k) {
            float d1 = dot4(kv[k], q1v);
            float d2 = dot4(kv[k], q2v);
            d1 = qxor1_add(d1); d1 = qxor2_add(d1); d1 = sxor4_add(d1);
            d2 = qxor1_add(d2); d2 = qxor2_add(d2); d2 = sxor4_add(d2);
            if (d4 == 0 && rr[k] < N) {
                int m = smask[rr[k]];
                s1[h][rr[k]] = m ? d1 * scale : NEG;
                s2[h][rr[k]] = m ? d2 * scale : NEG;
            }
        }
    }
    __syncthreads();

    // ---- P2: softmax.  wave w owns array (s1|s2)[w>>1]; no intra-phase sync ----
    {
        float* __restrict__ sarr = (wid & 1) ? s2[wid >> 1] : s1[wid >> 1];
        float mx = -INFINITY;
#pragma unroll
        for (int t = 0; t < 16; ++t) {
            int r = lane + 64 * t;
            if (r < N) mx = fmaxf(mx, sarr[r]);
        }
        mx = waveReduceMax(mx);
        float sum = 0.f;
#pragma unroll
        for (int t = 0; t < 16; ++t) {
            int r = lane + 64 * t;
            if (r < N) { float e = __expf(sarr[r] - mx); sarr[r] = e; sum += e; }
        }
        sum = waveReduceSum(sum);
        if (lane == 0) redSum[wid >> 1][wid & 1] = sum;
    }
    __syncthreads();

    // ---- P3: attn @ V.  Same tiling as P1. ----
    const float4* __restrict__ vb = (const float4*)(gv + (size_t)(b * H + h) * N * DH);
    float4 a1 = {0.f, 0.f, 0.f, 0.f}, a2 = {0.f, 0.f, 0.f, 0.f};
#pragma unroll 1
    for (int it = 0; it < 7; ++it) {
        const int rbase = it * 128 + r0;
        float4 vv[8];
#pragma unroll
        for (int k = 0; k < 8; ++k) vv[k] = vb[(rbase + 16 * k) * 8 + d4];
#pragma unroll
        for (int k = 0; k < 8; ++k) {
            int r = rbase + 16 * k;
            float p1 = s1[h][r], p2 = s2[h][r];
            a1.x = fmaf(p1, vv[k].x, a1.x); a1.y = fmaf(p1, vv[k].y, a1.y);
            a1.z = fmaf(p1, vv[k].z, a1.z); a1.w = fmaf(p1, vv[k].w, a1.w);
            a2.x = fmaf(p2, vv[k].x, a2.x); a2.y = fmaf(p2, vv[k].y, a2.y);
            a2.z = fmaf(p2, vv[k].z, a2.z); a2.w = fmaf(p2, vv[k].w, a2.w);
        }
    }
    {   // tail
        float4 vv[8]; int rr[8];
#pragma unroll
        for (int k = 0; k < 8; ++k) {
            rr[k] = 896 + r0 + 16 * k;
            vv[k] = (rr[k] < N) ? vb[rr[k] * 8 + d4] : make_float4(0.f, 0.f, 0.f, 0.f);
        }
#pragma unroll
        for (int k = 0; k < 8; ++k) {
            float p1 = (rr[k] < N) ? s1[h][rr[k]] : 0.f;
            float p2 = (rr[k] < N) ? s2[h][rr[k]] : 0.f;
            a1.x = fmaf(p1, vv[k].x, a1.x); a1.y = fmaf(p1, vv[k].y, a1.y);
            a1.z = fmaf(p1, vv[k].z, a1.z); a1.w = fmaf(p1, vv[k].w, a1.w);
            a2.x = fmaf(p2, vv[k].x, a2.x); a2.y = fmaf(p2, vv[k].y, a2.y);
            a2.z = fmaf(p2, vv[k].z, a2.z); a2.w = fmaf(p2, vv[k].w, a2.w);
        }
    }
#pragma unroll
    for (int off = 8; off <= 32; off <<= 1) {
        a1.x += __shfl_xor(a1.x, off, 64); a1.y += __shfl_xor(a1.y, off, 64);
        a1.z += __shfl_xor(a1.z, off, 64); a1.w += __shfl_xor(a1.w, off, 64);
        a2.x += __shfl_xor(a2.x, off, 64); a2.y += __shfl_xor(a2.y, off, 64);
        a2.z += __shfl_xor(a2.z, off, 64); a2.w += __shfl_xor(a2.w, off, 64);
    }
    if (lane < 8) {
        ((float4*)part1[h][half])[d4] = a1;
        ((float4*)part2[h][half])[d4] = a2;
    }
    __syncthreads();
    if (tid < 512) {
        int hh = (tid & 255) >> 5, d = tid & 31;
        if (tid < 256) {
            float rs = 1.f / redSum[hh][0];
            out1s[tid] = (part1[hh][0][d] + part1[hh][1][d]) * rs;
        } else {
            float rs = 1.f / redSum[hh][1];
            out2s[tid - 256] = (part2[hh][0][d] + part2[hh][1][d]) * rs;
        }
    }
    __syncthreads();

    // ---- P4: glimpse = out1 @ Wout, henc = out2 @ Wsa (split-K over 2 segs) ----
    {
        const int col = tid & 255;
        const int seg = (tid >> 8) & 1;
        const bool isG = tid < 512;
        const float* __restrict__ W  = isG ? Wout : Wsa;
        const float* __restrict__ xv = isG ? out1s : out2s;
        const float* __restrict__ Wp = W + (size_t)(seg * 128) * D + col;
        const float* __restrict__ xp = xv + seg * 128;
        float c0 = 0.f, c1 = 0.f, c2 = 0.f, c3 = 0.f;
#pragma unroll 2
        for (int i = 0; i < 128; i += 4) {
            c0 = fmaf(xp[i + 0], Wp[(i + 0) * D], c0);
            c1 = fmaf(xp[i + 1], Wp[(i + 1) * D], c1);
            c2 = fmaf(xp[i + 2], Wp[(i + 2) * D], c2);
            c3 = fmaf(xp[i + 3], Wp[(i + 3) * D], c3);
        }
        (isG ? gpart : hpart)[seg][col] = (c0 + c1) + (c2 + c3);
    }
    __syncthreads();
    if (tid < 256) {
        glimpse_s[tid] = gpart[0][tid] + gpart[1][tid];
    } else if (tid < 512) {
        int c = tid - 256;
        henc_out[b * D + c] = hpart[0][c] + hpart[1][c];
    }
    __syncthreads();

    // ---- P5: logits.  8-lane group owns a full 1KB row; 8 loads in flight ----
    {
        const int rs = lane >> 3;   // row within wave's 8-row group
        const int c  = lane & 7;    // column chunk
        float4 g[8];
#pragma unroll
        for (int j = 0; j < 8; ++j) g[j] = ((const float4*)glimpse_s)[c + 8 * j];
        const float4* __restrict__ lkb = (const float4*)(lk + (size_t)b * N * D);
#pragma unroll 1
        for (int it = 0; it < 8; ++it) {
            const int r = it * 128 + wid * 8 + rs;
            const bool ok = (r < N);
            float4 kv[8];
#pragma unroll
            for (int j = 0; j < 8; ++j)
                kv[j] = ok ? lkb[(size_t)r * 64 + c + 8 * j]
                           : make_float4(0.f, 0.f, 0.f, 0.f);
            float p = 0.f;
#pragma unroll
            for (int j = 0; j < 8; ++j) p += dot4(kv[j], g[j]);
            p = qxor1_add(p); p = qxor2_add(p); p = sxor4_add(p);
            if (c == 0 && ok) {
                float l = 10.0f * tanhf(p * 0.0625f);
                logits_s[r] = smask[r] ? l : NEG;
            }
        }
    }
    __syncthreads();

    // ---- P6: log_softmax over logits_s, write logp ----
    {
        float v = (tid < N) ? logits_s[tid] : -INFINITY;
        float m = waveReduceMax(v);
        if (lane == 0) redM[wid] = m;
        __syncthreads();
        m = redM[0];
#pragma unroll
        for (int i = 1; i < 16; ++i) m = fmaxf(m, redM[i]);
        float e = (tid < N) ? __expf(v - m) : 0.f;
        float s = waveReduceSum(e);
        if (lane == 0) redS[wid] = s;
        __syncthreads();
        s = 0.f;
#pragma unroll
        for (int i = 0; i < 16; ++i) s += redS[i];
        const float lse = m + logf(s);
        if (tid < N) logp[b * N + tid] = v - lse;
    }
}

extern "C" void kernel_launch(void* const* d_in, const int* in_sizes, int n_in,
                              void* d_out, int out_size, void* d_ws, size_t ws_size,
                              hipStream_t stream) {
    const float* ne   = (const float*)d_in[0];
    const float* gc   = (const float*)d_in[1];
    const float* gk   = (const float*)d_in[2];
    const float* gvv  = (const float*)d_in[3];
    const float* lk   = (const float*)d_in[4];
    const float* cap  = (const float*)d_in[5];
    const float* dem  = (const float*)d_in[6];
    const float* rem  = (const float*)d_in[7];
    const float* Wctx = (const float*)d_in[8];
    const float* Wout = (const float*)d_in[9];
    const float* Wsa  = (const float*)d_in[10];
    const int*   head = (const int*)d_in[11];
    const int*   feas = (const int*)d_in[12];
    float* out = (float*)d_out;

    float* ws    = (float*)d_ws;
    float* q1_ws = ws;            // B*D
    float* q2_ws = q1_ws + B * D; // B*D

    hipLaunchKernelGGL(k_ctx, dim3(B * 2), dim3(256), 0, stream,
                       ne, gc, cap, dem, rem, Wctx, head, q1_ws, q2_ws);
    hipLaunchKernelGGL(k_mega, dim3(B), dim3(1024), 0, stream,
                       gk, gvv, lk, q1_ws, q2_ws, Wout, Wsa, feas,
                       out, out + B * N);
}